// Round 13
// baseline (96.389 us; speedup 1.0000x reference)
//
#include <hip/hip_runtime.h>
#include <hip/hip_bf16.h>

#define N 1024
#define F 32
#define H 64
#define EA 8

typedef __attribute__((ext_vector_type(8))) short bf16x8;    // 8 bf16 in 4 VGPRs
typedef __attribute__((ext_vector_type(16))) float f32x16;   // MFMA C/D

union FragAB { bf16x8 v; unsigned u[4]; };

// pack two f32 -> one u32 (bf16(a) lo, bf16(b) hi), RNE
__device__ __forceinline__ unsigned pk(float a, float b) {
    union { __hip_bfloat162 h; unsigned u; } c;
    c.h = __float22bfloat162_rn(float2{a, b});
    return c.u;
}

__device__ __forceinline__ f32x16 zero16() {
    f32x16 z;
#pragma unroll
    for (int r = 0; r < 16; ++r) z[r] = 0.f;
    return z;
}

// Single fused kernel (R12 main loop + in-kernel MFMA precompute of nb/sv).
//   nb tile (32w x 64h) = X[wtile] @ Wd           -> 4 MFMAs, D IS the C-layout cnb
//   sv (4v x 64h)       = X[vbase+(m&3)] @ (Ws-Wd)-> 4 MFMAs; the &3 clamp makes
//                         every lane group's regs 0-3 hold sv[vbase+0..3] (no shuffle)
//   main loop: k=0..7: E x We; k8: 1.0 x sv; k9: (mask?0:-1) x 1e30; C-init = cnb
// out zeroed by a hipMemsetAsync graph node. Grid: 256 v-chunks x 8 w-quads = 2048
// blocks, 4 waves; partials via conflict-free ds_write + block reduce + atomicAdd.
__global__ __launch_bounds__(256, 4) void edge_fused(
    const int* __restrict__ A, const float* __restrict__ X,
    const float* __restrict__ Edge, const float* __restrict__ W,
    const float* __restrict__ b, float* __restrict__ out)
{
    const int lane = threadIdx.x & 63;
    const int wid  = threadIdx.x >> 6;
    const int lg   = lane >> 5;          // k-octet group
    const int ln   = lane & 31;          // A-row / B,C-col index
    const int wq   = blockIdx.x & 7;
    const int vch  = blockIdx.x >> 3;
    const int wbase = wq * 128 + wid * 32;
    const int vbase = vch * 4;

    __shared__ float part[4][2][4][64];  // [wid][lg][vi][col] = 8 KB

    // --- A-mask preloads ---
    const int* ap = A + (size_t)vbase * N + wbase + ln;
    int am[4];
#pragma unroll
    for (int vi = 0; vi < 4; ++vi) am[vi] = ap[(size_t)vi * N];

    // --- E depth-2 prefetch ring (v-stride = N*EA/4 = 2048 float4) ---
    const float4* ep = (const float4*)(Edge + ((size_t)vbase * N + wbase + ln) * EA);
    float4 eA[2], eB[2];
    eA[0] = ep[0];    eB[0] = ep[1];
    eA[1] = ep[2048]; eB[1] = ep[2049];

    // --- X A-fragments: aw (rows = w-tile), av (rows = vbase+(m&3)) ---
    // step s covers k = s*16 + lg*8 .. +8
    FragAB aw[2], av[2];
    {
        const float* xw = X + (size_t)(wbase + ln) * F;
        const float* xv = X + (size_t)(vbase + (ln & 3)) * F;
#pragma unroll
        for (int s = 0; s < 2; ++s) {
            const int k0 = s * 16 + lg * 8;
            const float4 w0 = *(const float4*)(xw + k0);
            const float4 w1 = *(const float4*)(xw + k0 + 4);
            aw[s].u[0] = pk(w0.x, w0.y); aw[s].u[1] = pk(w0.z, w0.w);
            aw[s].u[2] = pk(w1.x, w1.y); aw[s].u[3] = pk(w1.z, w1.w);
            const float4 v0 = *(const float4*)(xv + k0);
            const float4 v1 = *(const float4*)(xv + k0 + 4);
            av[s].u[0] = pk(v0.x, v0.y); av[s].u[1] = pk(v0.z, v0.w);
            av[s].u[2] = pk(v1.x, v1.y); av[s].u[3] = pk(v1.z, v1.w);
        }
    }

    // --- nb (C-layout) and sv via MFMA; Wd loads shared between fragments ---
    f32x16 cnb[2];
    unsigned sq0[4], sq1[4];
    {
#pragma unroll
        for (int half = 0; half < 2; ++half) {
            const int n = half * 32 + ln;
            FragAB bwd[2], bsd[2];
#pragma unroll
            for (int s = 0; s < 2; ++s) {
                const int k0 = s * 16 + lg * 8;
#pragma unroll
                for (int q = 0; q < 4; ++q) {
                    const float wd0 = W[(F + k0 + 2 * q) * H + n];
                    const float wd1 = W[(F + k0 + 2 * q + 1) * H + n];
                    const float ws0 = W[(k0 + 2 * q) * H + n];
                    const float ws1 = W[(k0 + 2 * q + 1) * H + n];
                    bwd[s].u[q] = pk(wd0, wd1);
                    bsd[s].u[q] = pk(ws0 - wd0, ws1 - wd1);
                }
            }
            f32x16 c = zero16();
            c = __builtin_amdgcn_mfma_f32_32x32x16_bf16(aw[0].v, bwd[0].v, c, 0, 0, 0);
            c = __builtin_amdgcn_mfma_f32_32x32x16_bf16(aw[1].v, bwd[1].v, c, 0, 0, 0);
            cnb[half] = c;
            f32x16 sD = zero16();
            sD = __builtin_amdgcn_mfma_f32_32x32x16_bf16(av[0].v, bsd[0].v, sD, 0, 0, 0);
            sD = __builtin_amdgcn_mfma_f32_32x32x16_bf16(av[1].v, bsd[1].v, sD, 0, 0, 0);
            const float bb = b[n];
#pragma unroll
            for (int vi = 0; vi < 4; ++vi) {
                const unsigned p = pk(sD[vi] + bb, 1e30f);   // {sv, 1e30} k8/k9 slot
                if (half) sq1[vi] = p; else sq0[vi] = p;
            }
        }
    }

    // --- B static: We[e][h] packed in k-octet 0; zeros in k-octet 1 ---
    FragAB bfr[2];
#pragma unroll
    for (int half = 0; half < 2; ++half) {
        const int n = half * 32 + ln;
#pragma unroll
        for (int q = 0; q < 4; ++q) {
            unsigned we = pk(W[(2 * F + 2 * q) * H + n], W[(2 * F + 2 * q + 1) * H + n]);
            bfr[half].u[q] = (lg == 0) ? we : 0u;
        }
    }

    // --- main vi loop (identical to R12) ---
#pragma unroll
    for (int vi = 0; vi < 4; ++vi) {
        const float4 ca = eA[vi & 1];
        const float4 cb = eB[vi & 1];
        if (vi < 2) {
            eA[vi & 1] = ep[(vi + 2) * 2048];
            eB[vi & 1] = ep[(vi + 2) * 2048 + 1];
        }

        FragAB afr;
        const unsigned mpat = am[vi] ? 0x00003f80u : 0xbf803f80u;  // k8=1.0, k9=0/-1
        afr.u[0] = (lg == 0) ? pk(ca.x, ca.y) : mpat;
        afr.u[1] = (lg == 0) ? pk(ca.z, ca.w) : 0u;
        afr.u[2] = (lg == 0) ? pk(cb.x, cb.y) : 0u;
        afr.u[3] = (lg == 0) ? pk(cb.z, cb.w) : 0u;

        FragAB b0 = bfr[0], b1 = bfr[1];
        if (lg) { b0.u[0] = sq0[vi]; b1.u[0] = sq1[vi]; }

        const f32x16 d0 = __builtin_amdgcn_mfma_f32_32x32x16_bf16(afr.v, b0.v, cnb[0], 0, 0, 0);
        const f32x16 d1 = __builtin_amdgcn_mfma_f32_32x32x16_bf16(afr.v, b1.v, cnb[1], 0, 0, 0);

        float p0 = 0.f, p1 = 0.f;
#pragma unroll
        for (int r = 0; r < 16; ++r) {
            p0 += fmaxf(d0[r], 0.f);
            p1 += fmaxf(d1[r], 0.f);
        }
        part[wid][lg][vi][ln]      = p0;   // lanes L and L+32 same bank: 2-way, free
        part[wid][lg][vi][32 + ln] = p1;
    }

    __syncthreads();
    {
        const int i  = threadIdx.x;
        const int vi = i >> 6, h = i & 63;
        float s = 0.f;
#pragma unroll
        for (int w4 = 0; w4 < 4; ++w4)
#pragma unroll
            for (int g = 0; g < 2; ++g) s += part[w4][g][vi][h];
        atomicAdd(&out[(size_t)(vbase + vi) * H + h], s);   // device-scope, safe
    }
}

extern "C" void kernel_launch(void* const* d_in, const int* in_sizes, int n_in,
                              void* d_out, int out_size, void* d_ws, size_t ws_size,
                              hipStream_t stream) {
    const int*   A    = (const int*)d_in[0];
    const float* X    = (const float*)d_in[1];
    const float* Edge = (const float*)d_in[2];
    const float* W    = (const float*)d_in[3];
    const float* b    = (const float*)d_in[4];
    float* out = (float*)d_out;

    hipMemsetAsync(out, 0, (size_t)out_size * sizeof(float), stream);  // graph memset node
    edge_fused<<<dim3(2048), dim3(256), 0, stream>>>(A, X, Edge, W, b, out);
}

// Round 14
// 92.367 us; speedup vs baseline: 1.0435x; 1.0435x over previous
//
#include <hip/hip_runtime.h>
#include <hip/hip_bf16.h>

#define N 1024
#define F 32
#define H 64
#define EA 8

typedef __attribute__((ext_vector_type(8))) short bf16x8;    // 8 bf16 in 4 VGPRs
typedef __attribute__((ext_vector_type(16))) float f32x16;   // MFMA C/D

union FragAB { bf16x8 v; unsigned u[4]; };

// pack two f32 -> one u32 (bf16(a) lo, bf16(b) hi), RNE
__device__ __forceinline__ unsigned pk(float a, float b) {
    union { __hip_bfloat162 h; unsigned u; } c;
    c.h = __float22bfloat162_rn(float2{a, b});
    return c.u;
}

// Kernel 1: sv[v,h] = b[h] + sum_f X[v,f]*(W[f,h]-W[32+f,h]); nb[v,h] = sum_f X[v,f]*W[32+f,h]
// Also zeroes out[]. One wave per v; lane = h.
__global__ __launch_bounds__(256) void precompute_terms(
    const float* __restrict__ X, const float* __restrict__ W, const float* __restrict__ b,
    float* __restrict__ sv, float* __restrict__ nb, float* __restrict__ out)
{
    const int lane = threadIdx.x & 63;
    const int wid  = threadIdx.x >> 6;
    const int v    = blockIdx.x * 4 + wid;

    float4 xr[8];
    const float4* xp = (const float4*)(X + (size_t)v * F);
#pragma unroll
    for (int i = 0; i < 8; ++i) xr[i] = xp[i];
    const float* xf = (const float*)xr;

    float s = b[lane];
    float n = 0.f;
#pragma unroll
    for (int f = 0; f < F; ++f) {
        float ws = W[f * H + lane];
        float wd = W[(F + f) * H + lane];
        s = fmaf(xf[f], ws - wd, s);
        n = fmaf(xf[f], wd, n);
    }
    const int idx = v * H + lane;
    sv[idx]  = s;
    nb[idx]  = n;
    out[idx] = 0.f;
}

// Kernel 2: MFMA 32x32x16 bf16 (best-known config, R12).
//   k=0..7 : E[v,w,e] x We[e,h];  k=8: 1.0 x sv[v,h];  k=9: (mask?0:-1) x 1e30
//   C-init = nb[w,h] in C-layout (v-invariant). Wave = 32-w tile x 64 h, loops 4 v.
// E in registers (depth-2 prefetch ring, compiler-scheduled vmcnt); A/sv batched
// up front; all loads issued by all lanes (branch-free schedule — exec-masked
// loads regressed in R10; fusion regressed in R13). Partials via conflict-free
// ds_write, block reduce, fan-in-8 device-scope atomicAdd (unsafeAtomicAdd
// silently dropped updates under load — R11).
// Grid: 256 v-chunks x 8 w-quads = 2048 blocks -> 8 blocks/CU, 8 waves/SIMD.
__global__ __launch_bounds__(256, 4) void edge_mfma(
    const int* __restrict__ A, const float* __restrict__ Edge, const float* __restrict__ W,
    const float* __restrict__ sv, const float* __restrict__ nb, float* __restrict__ out)
{
    const int lane = threadIdx.x & 63;
    const int wid  = threadIdx.x >> 6;
    const int lg   = lane >> 5;          // k-octet group (0: k=0-7, 1: k=8-15)
    const int ln   = lane & 31;          // A-row / B,C-col index
    const int wq   = blockIdx.x & 7;
    const int vch  = blockIdx.x >> 3;
    const int wbase = wq * 128 + wid * 32;
    const int vbase = vch * 4;

    __shared__ float part[4][2][4][64];  // [wid][lg][vi][col] = 8 KB

    // --- batched preloads: A-mask + sv for all 4 vi (latency hidden by setup) ---
    const int* ap = A + (size_t)vbase * N + wbase + ln;
    int am[4]; float s0v[4], s1v[4];
#pragma unroll
    for (int vi = 0; vi < 4; ++vi) {
        am[vi]  = ap[(size_t)vi * N];
        s0v[vi] = sv[(size_t)(vbase + vi) * H + ln];
        s1v[vi] = sv[(size_t)(vbase + vi) * H + 32 + ln];
    }

    // E row pointer for this lane's w (=wbase+ln); v-stride = N*EA/4 = 2048 float4
    const float4* ep = (const float4*)(Edge + ((size_t)vbase * N + wbase + ln) * EA);
    // depth-2 register prefetch ring
    float4 eA[2], eB[2];
    eA[0] = ep[0];    eB[0] = ep[1];
    eA[1] = ep[2048]; eB[1] = ep[2049];

    // B static: We[e][h] packed in k-octet 0; zeros in k-octet 1
    FragAB bfr[2];
#pragma unroll
    for (int half = 0; half < 2; ++half) {
        const int n = half * 32 + ln;
#pragma unroll
        for (int q = 0; q < 4; ++q) {
            unsigned we = pk(W[(2 * F + 2 * q) * H + n], W[(2 * F + 2 * q + 1) * H + n]);
            bfr[half].u[q] = (lg == 0) ? we : 0u;
        }
    }

    // C-init = nb in MFMA C-layout: row=(r&3)+8*(r>>2)+4*lg, col=ln(+32*half)
    f32x16 cnb[2];
#pragma unroll
    for (int half = 0; half < 2; ++half)
#pragma unroll
        for (int r = 0; r < 16; ++r) {
            const int row = (r & 3) + 8 * (r >> 2) + 4 * lg;
            cnb[half][r] = nb[(size_t)(wbase + row) * H + half * 32 + ln];
        }

#pragma unroll
    for (int vi = 0; vi < 4; ++vi) {
        const float4 ca = eA[vi & 1];
        const float4 cb = eB[vi & 1];
        if (vi < 2) {
            eA[vi & 1] = ep[(vi + 2) * 2048];
            eB[vi & 1] = ep[(vi + 2) * 2048 + 1];
        }

        FragAB afr;
        const unsigned mpat = am[vi] ? 0x00003f80u : 0xbf803f80u;  // k8=1.0, k9=0/-1
        afr.u[0] = (lg == 0) ? pk(ca.x, ca.y) : mpat;
        afr.u[1] = (lg == 0) ? pk(ca.z, ca.w) : 0u;
        afr.u[2] = (lg == 0) ? pk(cb.x, cb.y) : 0u;
        afr.u[3] = (lg == 0) ? pk(cb.z, cb.w) : 0u;

        FragAB b0 = bfr[0], b1 = bfr[1];
        if (lg) { b0.u[0] = pk(s0v[vi], 1e30f); b1.u[0] = pk(s1v[vi], 1e30f); }

        const f32x16 d0 = __builtin_amdgcn_mfma_f32_32x32x16_bf16(afr.v, b0.v, cnb[0], 0, 0, 0);
        const f32x16 d1 = __builtin_amdgcn_mfma_f32_32x32x16_bf16(afr.v, b1.v, cnb[1], 0, 0, 0);

        float p0 = 0.f, p1 = 0.f;
#pragma unroll
        for (int r = 0; r < 16; ++r) {
            p0 += fmaxf(d0[r], 0.f);
            p1 += fmaxf(d1[r], 0.f);
        }
        part[wid][lg][vi][ln]      = p0;   // lanes L and L+32 same bank: 2-way, free
        part[wid][lg][vi][32 + ln] = p1;
    }

    __syncthreads();
    {
        const int i  = threadIdx.x;
        const int vi = i >> 6, h = i & 63;
        float s = 0.f;
#pragma unroll
        for (int w4 = 0; w4 < 4; ++w4)
#pragma unroll
            for (int g = 0; g < 2; ++g) s += part[w4][g][vi][h];
        atomicAdd(&out[(size_t)(vbase + vi) * H + h], s);   // device-scope, safe
    }
}

extern "C" void kernel_launch(void* const* d_in, const int* in_sizes, int n_in,
                              void* d_out, int out_size, void* d_ws, size_t ws_size,
                              hipStream_t stream) {
    const int*   A    = (const int*)d_in[0];
    const float* X    = (const float*)d_in[1];
    const float* Edge = (const float*)d_in[2];
    const float* W    = (const float*)d_in[3];
    const float* b    = (const float*)d_in[4];
    float* out = (float*)d_out;

    float* sv = (float*)d_ws;
    float* nb = sv + N * H;

    precompute_terms<<<dim3(256), dim3(256), 0, stream>>>(X, W, b, sv, nb, out);
    edge_mfma<<<dim3(2048), dim3(256), 0, stream>>>(A, Edge, W, sv, nb, out);
}